// Round 3
// baseline (1323.345 us; speedup 1.0000x reference)
//
#include <hip/hip_runtime.h>
#include <hip/hip_bf16.h>

#define ITER_TIME 32
#define DECAY 0.9f

typedef __attribute__((ext_vector_type(8))) short short8;
typedef __attribute__((ext_vector_type(4))) float f32x4;
typedef unsigned short ushort_t;

// ---------------------------------------------------------------------------
// Convert f32 -> bf16 elementwise (for x)
// ---------------------------------------------------------------------------
__global__ void conv_f32_bf16(const float* __restrict__ in,
                              __hip_bfloat16* __restrict__ out, int n) {
    int i = blockIdx.x * 256 + threadIdx.x;
    if (i < n) out[i] = __float2bfloat16(in[i]);
}

// ---------------------------------------------------------------------------
// Fused convert + transpose: f32 in [R][C] -> bf16 out [C][R]
// ---------------------------------------------------------------------------
__global__ void transpose_f32_bf16(const float* __restrict__ in,
                                   __hip_bfloat16* __restrict__ out, int R,
                                   int C) {
    __shared__ float tile[32][33];
    int tx = threadIdx.x, ty = threadIdx.y;
    size_t x = blockIdx.x * 32 + tx;  // col in `in`
    size_t y = blockIdx.y * 32 + ty;  // row in `in`
    tile[ty][tx] = in[y * C + x];
    __syncthreads();
    size_t ox = blockIdx.y * 32 + tx;  // col in `out` (= row in `in`)
    size_t oy = blockIdx.x * 32 + ty;  // row in `out` (= col in `in`)
    out[oy * R + ox] = __float2bfloat16(tile[tx][ty]);
}

// ---------------------------------------------------------------------------
// Split-K GEMM: C_part[ks] = A[M=256 x K] * B (given as B^T rows [N][K]),
// bf16 inputs, f32 partials out.
// grid: (2, n_tiles, KS), block 256 (4 waves), tile 128x128, BK=64.
// Tiles with by >= Nmain/128 take columns from BT2 (the W_f appendage) and
// write to C2p instead.
// ---------------------------------------------------------------------------
__global__ __launch_bounds__(256)
void gemm_splitk(const ushort_t* __restrict__ A,    // [256][K] bf16
                 const ushort_t* __restrict__ BT,   // [Nmain][K] bf16
                 const ushort_t* __restrict__ BT2,  // [N2][K] bf16 (or null)
                 float* __restrict__ Cp,            // [KS][256][Nmain]
                 float* __restrict__ C2p,           // [KS][256][N2]
                 int K, int klen, int Nmain, int N2) {
    const int M = 256;
    __shared__ __attribute__((aligned(16))) ushort_t As[128 * 72];
    __shared__ __attribute__((aligned(16))) ushort_t Bs[128 * 72];

    int m0 = blockIdx.x * 128;
    int by = blockIdx.y;
    int ks = blockIdx.z;
    int ntile_main = Nmain >> 7;
    bool isB2 = (by >= ntile_main);
    const ushort_t* Bsrc = isB2 ? BT2 + (size_t)((by - ntile_main) * 128) * K
                                : BT + (size_t)(by * 128) * K;

    int t = threadIdx.x;
    int wave = t >> 6, lane = t & 63;
    int quad = lane >> 4, l16 = lane & 15;
    int wm = (wave >> 1) * 64, wn = (wave & 1) * 64;

    f32x4 acc[4][4];
#pragma unroll
    for (int i = 0; i < 4; i++)
#pragma unroll
        for (int j = 0; j < 4; j++) acc[i][j] = (f32x4){0.f, 0.f, 0.f, 0.f};

    int ldr = t >> 3;        // 0..31 (row within 32-row staging group)
    int ldc = (t & 7) * 8;   // 0,8,..,56 (k offset, 8 elems = 16B)

    int k0 = ks * klen;
    int iters = klen >> 6;
    for (int it = 0; it < iters; ++it) {
        int kk = k0 + it * 64;
#pragma unroll
        for (int i = 0; i < 4; ++i) {
            int r = ldr + i * 32;
            *(short8*)&As[r * 72 + ldc] =
                *(const short8*)&A[(size_t)(m0 + r) * K + kk + ldc];
            *(short8*)&Bs[r * 72 + ldc] =
                *(const short8*)&Bsrc[(size_t)r * K + kk + ldc];
        }
        __syncthreads();
#pragma unroll
        for (int kstep = 0; kstep < 2; ++kstep) {
            int ko = kstep * 32 + quad * 8;
            short8 af[4], bfr[4];
#pragma unroll
            for (int i = 0; i < 4; i++)
                af[i] = *(const short8*)&As[(wm + i * 16 + l16) * 72 + ko];
#pragma unroll
            for (int j = 0; j < 4; j++)
                bfr[j] = *(const short8*)&Bs[(wn + j * 16 + l16) * 72 + ko];
#pragma unroll
            for (int i = 0; i < 4; i++)
#pragma unroll
                for (int j = 0; j < 4; j++)
                    acc[i][j] = __builtin_amdgcn_mfma_f32_16x16x32_bf16(
                        af[i], bfr[j], acc[i][j], 0, 0, 0);
        }
        __syncthreads();
    }

    // Epilogue: C/D layout col = lane&15, row = quad*4 + reg
#pragma unroll
    for (int i = 0; i < 4; i++) {
#pragma unroll
        for (int j = 0; j < 4; j++) {
            int gcol = by * 128 + wn + j * 16 + l16;
#pragma unroll
            for (int rr = 0; rr < 4; ++rr) {
                int grow = m0 + wm + i * 16 + quad * 4 + rr;
                float v = acc[i][j][rr];
                if (!isB2) {
                    Cp[(size_t)ks * M * Nmain + (size_t)grow * Nmain + gcol] = v;
                } else {
                    int c2 = gcol - Nmain;
                    C2p[(size_t)ks * M * N2 + (size_t)grow * N2 + c2] = v;
                }
            }
        }
    }
}

// ---------------------------------------------------------------------------
// Per-step elementwise: reduce r partials, leaky-integrate, relu, emit act
// (f32); also reduce f partials from the PREVIOUS step's GEMM into
// out[:,t-1,:] (f32). At t==0 folds the bias into i_ (writes back); u0=r0=0.
// ---------------------------------------------------------------------------
__global__ void elem_step(float* __restrict__ i_, float* __restrict__ u,
                          __hip_bfloat16* __restrict__ a,
                          const float* __restrict__ rp,
                          const float* __restrict__ fp,
                          const float* __restrict__ bias,
                          float* __restrict__ out, float* __restrict__ act,
                          int t) {
    int id = blockIdx.x * 256 + threadIdx.x;
    const int NU = 256 * 4096;
    if (id < NU) {
        if (t >= ITER_TIME) return;  // final launch only reduces f
        int b = id >> 12, n = id & 4095;
        float un;
        if (t == 0) {
            float iv = i_[id] + bias[n];
            i_[id] = iv;  // subsequent steps read biased i_
            un = iv;      // u0 = 0, r0 = 0
        } else {
            un = DECAY * u[id] + i_[id] + rp[id] + rp[NU + id] +
                 rp[2 * NU + id] + rp[3 * NU + id];
        }
        u[id] = un;
        float ar = un > 0.f ? un : 0.f;
        a[id] = __float2bfloat16(ar);
        act[(size_t)b * (ITER_TIME * 4096) + (size_t)t * 4096 + n] = un;
    } else {
        if (t == 0) return;  // no f produced yet
        int id2 = id - NU;   // < 65536
        const int NF = 256 * 256;
        int b = id2 >> 8, d = id2 & 255;
        float fv = fp[id2] + fp[NF + id2] + fp[2 * NF + id2] + fp[3 * NF + id2];
        out[(size_t)b * (ITER_TIME * 256) + (size_t)(t - 1) * 256 + d] = fv;
    }
}

// ---------------------------------------------------------------------------
// Workspace layout (peak 0x3D80000 = 61.5 MB):
//   i_   0x0000000  4 MB  f32 [256][4096]
//   u    0x0400000  4 MB  f32 [256][4096]
//   a    0x0800000  2 MB  bf16 [256][4096]
//   rp   0x0A00000 16 MB  f32 [4][256][4096]   (WiT transiently lives here)
//   fp   0x1A00000  1 MB  f32 [4][256][256]
//   WrT  0x1B00000 32 MB  bf16 [4096][4096]
//   WfT  0x3B00000  2 MB  bf16 [256][4096]
//   xb   0x3D00000 .5 MB  bf16 [256][1024]
// ---------------------------------------------------------------------------
extern "C" void kernel_launch(void* const* d_in, const int* in_sizes, int n_in,
                              void* d_out, int out_size, void* d_ws,
                              size_t ws_size, hipStream_t stream) {
    const float* x = (const float*)d_in[0];    // [256][1024] f32
    const float* Wi = (const float*)d_in[1];   // [1024][4096] f32
    const float* bb = (const float*)d_in[2];   // [4096] f32
    const float* Wr = (const float*)d_in[3];   // [4096][4096] f32
    const float* Wf = (const float*)d_in[4];   // [4096][256] f32

    float* out = (float*)d_out;                        // [256][32][256]
    float* act = out + (size_t)256 * ITER_TIME * 256;  // [256][32][4096]

    char* ws = (char*)d_ws;
    float* i_ = (float*)(ws + 0x0);
    float* u = (float*)(ws + 0x400000);
    __hip_bfloat16* a = (__hip_bfloat16*)(ws + 0x800000);
    float* rp = (float*)(ws + 0xA00000);
    float* fp = (float*)(ws + 0x1A00000);
    __hip_bfloat16* WrT = (__hip_bfloat16*)(ws + 0x1B00000);
    __hip_bfloat16* WfT = (__hip_bfloat16*)(ws + 0x3B00000);
    __hip_bfloat16* xb = (__hip_bfloat16*)(ws + 0x3D00000);
    __hip_bfloat16* WiT = (__hip_bfloat16*)(ws + 0xA00000);  // transient in rp

    conv_f32_bf16<<<1024, 256, 0, stream>>>(x, xb, 256 * 1024);
    dim3 tb(32, 32);
    transpose_f32_bf16<<<dim3(128, 32), tb, 0, stream>>>(Wi, WiT, 1024, 4096);
    transpose_f32_bf16<<<dim3(128, 128), tb, 0, stream>>>(Wr, WrT, 4096, 4096);
    transpose_f32_bf16<<<dim3(8, 128), tb, 0, stream>>>(Wf, WfT, 4096, 256);

    // i_ = x @ W_i (no split-K; writes i_ directly as the single partial)
    gemm_splitk<<<dim3(2, 32, 1), 256, 0, stream>>>(
        (const ushort_t*)xb, (const ushort_t*)WiT, nullptr, i_, nullptr, 1024,
        1024, 4096, 256);

    for (int t = 0; t <= ITER_TIME; ++t) {
        elem_step<<<4352, 256, 0, stream>>>(i_, u, a, rp, fp, bb, out, act, t);
        if (t < ITER_TIME) {
            // a @ [W_r | W_f]: N tiles 0..31 -> W_r, 32..33 -> W_f.
            // K=4096 split 4 ways (klen=1024).
            gemm_splitk<<<dim3(2, 34, 4), 256, 0, stream>>>(
                (const ushort_t*)a, (const ushort_t*)WrT,
                (const ushort_t*)WfT, rp, fp, 4096, 1024, 4096, 256);
        }
    }
}